// Round 16
// baseline (127.934 us; speedup 1.0000x reference)
//
#include <hip/hip_runtime.h>

// Truncated signature, depth=3, C=8, B=512, L=8192.
// Kernel 1 (R15 + conflict-free A-write swizzle):
//   one wave per (sample,chunk); lane (a,b)=(lane>>3,lane&7) owns S2[a][b],
//   S3[a][b][0..7]. Direct form: S3[k] += cf*dx2[k][u], cf=S2+S1*db/2+da*db/6.
//   dx/2 staged in BOTH LDS layouts (per-wave private, NO barriers):
//     Bc [c][t] stride 68                -> per-lane da/db b128 reads
//     A  [t'][c] 4+4 split, t'=t^((t>>3)&3) XOR swizzle
//        -> uniform b128 broadcast reads at compile-time offsets;
//        -> scalar transpose WRITES hit all 32 banks (2-way total = free).
//   4-step blocks; block j+1's 10 b128 operands prefetched into named A/B
//   register sets while block j computes.
// Kernel 2: per-sample in-order Chen combine of the G chunk signatures.

typedef float f2 __attribute__((ext_vector_type(2)));

constexpr int B_ = 512;
constexpr int C_ = 8;
constexpr int L_ = 8192;
constexpr int NINC = L_ - 1;      // 8191 increments
constexpr int SIGDIM = 584;       // 8 + 64 + 512
constexpr int TILE = 64;          // steps per LDS tile
constexpr int BSTR = 68;          // Bc row stride (floats)
constexpr int AHOFF = 264;        // A high-half offset (floats); %32 = 8
constexpr int AWSZ = 520;
constexpr int BWSZ = C_ * BSTR;   // 544

__host__ __device__ constexpr int SW(int t) { return t ^ ((t >> 3) & 3); }

// load block J's operands (4 steps) into register set SET (swizzled A offsets
// are compile-time after unroll)
#define LDP(SET, J)                                                   \
  do {                                                                \
    SET##p0 = *(const float4*)(as_ + SW((J) * 4 + 0) * 4);            \
    SET##p1 = *(const float4*)(as_ + SW((J) * 4 + 1) * 4);            \
    SET##p2 = *(const float4*)(as_ + SW((J) * 4 + 2) * 4);            \
    SET##p3 = *(const float4*)(as_ + SW((J) * 4 + 3) * 4);            \
    SET##q0 = *(const float4*)(as_ + AHOFF + SW((J) * 4 + 0) * 4);    \
    SET##q1 = *(const float4*)(as_ + AHOFF + SW((J) * 4 + 1) * 4);    \
    SET##q2 = *(const float4*)(as_ + AHOFF + SW((J) * 4 + 2) * 4);    \
    SET##q3 = *(const float4*)(as_ + AHOFF + SW((J) * 4 + 3) * 4);    \
    SET##av = *(const float4*)(pa + (J) * 4);                         \
    SET##bv = *(const float4*)(pb + (J) * 4);                         \
  } while (0)

// one step on halved increments; true-scale cf/S2/S1; S3 as f2 k-pairs.
#define ST1(DA, DB, PLO, PHI)                                              \
  do {                                                                     \
    const float w_ = __builtin_fmaf((DA), (2.f / 3.f), s1a);               \
    const float z_ = __builtin_fmaf((DA), (4.f / 3.f), s1a);               \
    const float cf = __builtin_fmaf((DB), w_, S2);                         \
    S2  = __builtin_fmaf((DB), z_, cf);                                    \
    s1a = __builtin_fmaf((DA), 2.f, s1a);                                  \
    const f2 cf2 = {cf, cf};                                               \
    S3p[0] = __builtin_elementwise_fma(cf2, f2{(PLO).x, (PLO).y}, S3p[0]); \
    S3p[1] = __builtin_elementwise_fma(cf2, f2{(PLO).z, (PLO).w}, S3p[1]); \
    S3p[2] = __builtin_elementwise_fma(cf2, f2{(PHI).x, (PHI).y}, S3p[2]); \
    S3p[3] = __builtin_elementwise_fma(cf2, f2{(PHI).z, (PHI).w}, S3p[3]); \
  } while (0)

#define CB(SET)                                        \
  do {                                                 \
    ST1(SET##av.x, SET##bv.x, SET##p0, SET##q0);       \
    ST1(SET##av.y, SET##bv.y, SET##p1, SET##q1);       \
    ST1(SET##av.z, SET##bv.z, SET##p2, SET##q2);       \
    ST1(SET##av.w, SET##bv.w, SET##p3, SET##q3);       \
  } while (0)

__global__ __launch_bounds__(256, 8)
void sig_chunks_kernel(const float* __restrict__ path, float* __restrict__ csig,
                       int G, int CPC) {
  __shared__ __align__(16) float As[4][AWSZ];
  __shared__ __align__(16) float Bs[4][BWSZ];
  const int wid  = __builtin_amdgcn_readfirstlane((int)(threadIdx.x >> 6));
  const int lane = (int)(threadIdx.x & 63);
  const int ia = lane >> 3;   // 'a' == staging channel
  const int ib = lane & 7;    // 'b' == staging position
  const int wglob = __builtin_amdgcn_readfirstlane((int)blockIdx.x) * 4 + wid;
  const int samp = wglob / G;
  const int g    = wglob - samp * G;
  const int ts = g * CPC;
  const int te = (ts + CPC < NINC) ? (ts + CPC) : NINC;   // exclusive end
  const float* pbase = path + (size_t)samp * (C_ * L_);
  float* as_ = As[wid];
  float* bs  = Bs[wid];

  const int si = ib;
  const float* prow = pbase + ia * L_;
  const int grp = lane & ~7;
  const float* pa = bs + ia * BSTR;
  const float* pb = bs + ib * BSTR;

  // swizzled per-lane A-write pointers (constant for the whole kernel):
  // lane (ia,si) writes step t = h*32 + si*4 + j at swizzled slot
  //   h*32 + si*4 + (j ^ r),  r = (si>>1)&3  (XOR only touches bits[1:0])
  const int rsw = (si >> 1) & 3;
  float* awb = as_ + (ia >> 2) * AHOFF + (ia & 3);
  float* aw0 = awb + (si * 4 + (0 ^ rsw)) * 4;
  float* aw1 = awb + (si * 4 + (1 ^ rsw)) * 4;
  float* aw2 = awb + (si * 4 + (2 ^ rsw)) * 4;
  float* aw3 = awb + (si * 4 + (3 ^ rsw)) * 4;

  f2 S3p[4];
#pragma unroll
  for (int k = 0; k < 4; ++k) S3p[k] = f2{0.f, 0.f};
  float S2 = 0.f, s1a = 0.f;

  const int ntiles = (CPC + TILE - 1) / TILE;   // uniform across grid

  // prologue: prefetch tile 0 + boundary
  float4 r0 = *(const float4*)(prow + ts + si * 4);
  float4 r1 = *(const float4*)(prow + ts + 32 + si * 4);
  float bnd = prow[ts + TILE];

  float4 Ap0, Ap1, Ap2, Ap3, Aq0, Aq1, Aq2, Aq3, Aav, Abv;
  float4 Bp0, Bp1, Bp2, Bp3, Bq0, Bq1, Bq2, Bq3, Bav, Bbv;

  for (int tt = 0; tt < ntiles; ++tt) {
    const int t0 = ts + tt * TILE;
    const int cnt_ = te - t0;
    const int cnt = (cnt_ < TILE) ? cnt_ : TILE;

    // ---- stage tile tt from regs: halved diffs into both LDS layouts ----
    {
      const float4 v0 = r0, v1 = r1;
      const float sA = __shfl(v0.x, lane + 1);
      const float sB = __shfl(v1.x, grp);
      const float sC = __shfl(v1.x, lane + 1);
      const float n0 = (si == 7) ? sB : sA;
      const float n1 = (si == 7) ? bnd : sC;
      float4 d0, d1;
      d0.x = (v0.y - v0.x) * 0.5f;
      d0.y = (v0.z - v0.y) * 0.5f;
      d0.z = (v0.w - v0.z) * 0.5f;
      d0.w = (n0 - v0.w) * 0.5f;
      d1.x = (v1.y - v1.x) * 0.5f;
      d1.y = (v1.z - v1.y) * 0.5f;
      d1.z = (v1.w - v1.z) * 0.5f;
      d1.w = (n1 - v1.w) * 0.5f;
      *(float4*)(bs + ia * BSTR + si * 4) = d0;
      *(float4*)(bs + ia * BSTR + 32 + si * 4) = d1;
      // swizzled transpose writes: d0 at t=si*4+j, d1 at t=32+si*4+j
      aw0[0] = d0.x;
      aw1[0] = d0.y;
      aw2[0] = d0.z;
      aw3[0] = d0.w;
      aw0[128] = d1.x;
      aw1[128] = d1.y;
      aw2[128] = d1.z;
      aw3[128] = d1.w;
    }

    // ---- prefetch tile tt+1 ----
    if (tt + 1 < ntiles) {
      const int t1g = t0 + TILE;
      r0 = *(const float4*)(prow + t1g + si * 4);
      r1 = *(const float4*)(prow + t1g + 32 + si * 4);
      const int bn = t1g + TILE;
      bnd = (bn < L_) ? prow[bn] : 0.f;
    }

    // ---- compute tile tt: 16 4-step blocks, A/B register double-buffer ----
    if (cnt == TILE) {
      LDP(A, 0);
#pragma unroll
      for (int jj = 0; jj < 8; ++jj) {
        LDP(B, jj * 2 + 1);
        CB(A);
        if (jj < 7) { LDP(A, jj * 2 + 2); }
        CB(B);
      }
    } else {
      // tail tile (only the last chunk's last tile, cnt=63): cold path
      for (int blk = 0; blk < 8; ++blk) {
        const int u0 = blk * 8;
        int m = cnt - u0; if (m > 8) m = 8;
        if (m <= 0) break;
        const float4 a0 = *(const float4*)(pa + u0);
        const float4 a1 = *(const float4*)(pa + u0 + 4);
        const float4 b0 = *(const float4*)(pb + u0);
        const float4 b1 = *(const float4*)(pb + u0 + 4);
        const float da[8] = {a0.x, a0.y, a0.z, a0.w, a1.x, a1.y, a1.z, a1.w};
        const float db[8] = {b0.x, b0.y, b0.z, b0.w, b1.x, b1.y, b1.z, b1.w};
#pragma unroll
        for (int u = 0; u < 8; ++u) {
          if (u < m) {
            const int tsw = SW(u0 + u);
            const float4 PLO = *(const float4*)(as_ + tsw * 4);
            const float4 PHI = *(const float4*)(as_ + AHOFF + tsw * 4);
            ST1(da[u], db[u], PLO, PHI);
          }
        }
      }
    }
  }

  float* cs = csig + ((size_t)samp * G + g) * SIGDIM;
  if (ib == 0) cs[ia] = s1a;
  cs[8 + lane] = S2;
  float4 o0, o1;
  o0.x = 2.f * S3p[0].x; o0.y = 2.f * S3p[0].y;
  o0.z = 2.f * S3p[1].x; o0.w = 2.f * S3p[1].y;
  o1.x = 2.f * S3p[2].x; o1.y = 2.f * S3p[2].y;
  o1.z = 2.f * S3p[3].x; o1.w = 2.f * S3p[3].y;
  *(float4*)(cs + 72 + lane * 8)     = o0;
  *(float4*)(cs + 72 + lane * 8 + 4) = o1;
}

__global__ __launch_bounds__(256)
void sig_combine_kernel(const float* __restrict__ csig, float* __restrict__ out, int G) {
  const int wid  = __builtin_amdgcn_readfirstlane((int)(threadIdx.x >> 6));
  const int lane = (int)(threadIdx.x & 63);
  const int ia = lane >> 3, ib = lane & 7;
  const int samp = __builtin_amdgcn_readfirstlane((int)blockIdx.x) * 4 + wid;
  const float* base = csig + (size_t)samp * G * SIGDIM;

  float R1a = base[ia];
  float R2  = base[8 + lane];
  float R3[8];
#pragma unroll
  for (int k = 0; k < 8; ++k) R3[k] = base[72 + lane * 8 + k];

  for (int g = 1; g < G; ++g) {
    const float* T = base + g * SIGDIM;
    float sT1[8];
#pragma unroll
    for (int k = 0; k < 8; ++k) sT1[k] = T[k];
    const float T1a  = T[ia];
    const float T1b  = T[ib];
    const float T2ab = T[8 + lane];
    float T2b[8], T3v[8];
#pragma unroll
    for (int k = 0; k < 8; ++k) T2b[k] = T[8 + ib * 8 + k];
#pragma unroll
    for (int k = 0; k < 8; ++k) T3v[k] = T[72 + lane * 8 + k];
    const float R1o = R1a, R2o = R2;
#pragma unroll
    for (int k = 0; k < 8; ++k)
      R3[k] += T3v[k] + R1o * T2b[k] + R2o * sT1[k];
    R2  += T2ab + R1o * T1b;
    R1a += T1a;
  }

  float* o = out + (size_t)samp * SIGDIM;
  if (ib == 0) o[ia] = R1a;
  o[8 + lane] = R2;
#pragma unroll
  for (int k = 0; k < 8; ++k) o[72 + lane * 8 + k] = R3[k];
}

extern "C" void kernel_launch(void* const* d_in, const int* in_sizes, int n_in,
                              void* d_out, int out_size, void* d_ws, size_t ws_size,
                              hipStream_t stream) {
  (void)in_sizes; (void)n_in; (void)out_size;
  const float* path = (const float*)d_in[0];
  float* out = (float*)d_out;
  float* ws  = (float*)d_ws;

  int G = 16;
  while (G > 1 && (size_t)B_ * G * SIGDIM * sizeof(float) > ws_size) G >>= 1;
  const int CPC = (NINC + G - 1) / G;   // increments per chunk

  sig_chunks_kernel<<<dim3(B_ * G / 4), dim3(256), 0, stream>>>(path, ws, G, CPC);
  sig_combine_kernel<<<dim3(B_ / 4), dim3(256), 0, stream>>>(ws, out, G);
}

// Round 17
// 114.492 us; speedup vs baseline: 1.1174x; 1.1174x over previous
//
#include <hip/hip_runtime.h>

// Truncated signature, depth=3, C=8, B=512, L=8192.
// Kernel 1 (R15 pipeline + R16 conflict-free A-write swizzle, (256,3) bound):
//   one wave per (sample,chunk); lane (a,b)=(lane>>3,lane&7) owns S2[a][b],
//   S3[a][b][0..7]. Direct form: S3[k] += cf*dx2[k][u], cf=S2+S1*db/2+da*db/6.
//   dx/2 staged in BOTH LDS layouts (per-wave private, NO barriers):
//     Bc [c][t] stride 68                -> per-lane da/db b128 reads
//     A  [t'][c] 4+4 split, t'=t^((t>>3)&3) XOR swizzle
//        -> uniform b128 broadcast reads at compile-time offsets;
//        -> scalar transpose WRITES spread across all 32 banks (2-way = free).
//   4-step blocks; block j+1's 10 b128 operands prefetched into named A/B
//   register sets while block j computes. launch_bounds(256,3): the ~80-VGPR
//   working set must NOT be squeezed (R16's (256,8) caused scratch spills).
// Kernel 2: per-sample in-order Chen combine of the G chunk signatures.

typedef float f2 __attribute__((ext_vector_type(2)));

constexpr int B_ = 512;
constexpr int C_ = 8;
constexpr int L_ = 8192;
constexpr int NINC = L_ - 1;      // 8191 increments
constexpr int SIGDIM = 584;       // 8 + 64 + 512
constexpr int TILE = 64;          // steps per LDS tile
constexpr int BSTR = 68;          // Bc row stride (floats)
constexpr int AHOFF = 264;        // A high-half offset (floats); %32 = 8
constexpr int AWSZ = 520;
constexpr int BWSZ = C_ * BSTR;   // 544

__host__ __device__ constexpr int SW(int t) { return t ^ ((t >> 3) & 3); }

// load block J's operands (4 steps) into register set SET (swizzled A offsets
// are compile-time after unroll)
#define LDP(SET, J)                                                   \
  do {                                                                \
    SET##p0 = *(const float4*)(as_ + SW((J) * 4 + 0) * 4);            \
    SET##p1 = *(const float4*)(as_ + SW((J) * 4 + 1) * 4);            \
    SET##p2 = *(const float4*)(as_ + SW((J) * 4 + 2) * 4);            \
    SET##p3 = *(const float4*)(as_ + SW((J) * 4 + 3) * 4);            \
    SET##q0 = *(const float4*)(as_ + AHOFF + SW((J) * 4 + 0) * 4);    \
    SET##q1 = *(const float4*)(as_ + AHOFF + SW((J) * 4 + 1) * 4);    \
    SET##q2 = *(const float4*)(as_ + AHOFF + SW((J) * 4 + 2) * 4);    \
    SET##q3 = *(const float4*)(as_ + AHOFF + SW((J) * 4 + 3) * 4);    \
    SET##av = *(const float4*)(pa + (J) * 4);                         \
    SET##bv = *(const float4*)(pb + (J) * 4);                         \
  } while (0)

// one step on halved increments; true-scale cf/S2/S1; S3 as f2 k-pairs.
#define ST1(DA, DB, PLO, PHI)                                              \
  do {                                                                     \
    const float w_ = __builtin_fmaf((DA), (2.f / 3.f), s1a);               \
    const float z_ = __builtin_fmaf((DA), (4.f / 3.f), s1a);               \
    const float cf = __builtin_fmaf((DB), w_, S2);                         \
    S2  = __builtin_fmaf((DB), z_, cf);                                    \
    s1a = __builtin_fmaf((DA), 2.f, s1a);                                  \
    const f2 cf2 = {cf, cf};                                               \
    S3p[0] = __builtin_elementwise_fma(cf2, f2{(PLO).x, (PLO).y}, S3p[0]); \
    S3p[1] = __builtin_elementwise_fma(cf2, f2{(PLO).z, (PLO).w}, S3p[1]); \
    S3p[2] = __builtin_elementwise_fma(cf2, f2{(PHI).x, (PHI).y}, S3p[2]); \
    S3p[3] = __builtin_elementwise_fma(cf2, f2{(PHI).z, (PHI).w}, S3p[3]); \
  } while (0)

#define CB(SET)                                        \
  do {                                                 \
    ST1(SET##av.x, SET##bv.x, SET##p0, SET##q0);       \
    ST1(SET##av.y, SET##bv.y, SET##p1, SET##q1);       \
    ST1(SET##av.z, SET##bv.z, SET##p2, SET##q2);       \
    ST1(SET##av.w, SET##bv.w, SET##p3, SET##q3);       \
  } while (0)

__global__ __launch_bounds__(256, 3)
void sig_chunks_kernel(const float* __restrict__ path, float* __restrict__ csig,
                       int G, int CPC) {
  __shared__ __align__(16) float As[4][AWSZ];
  __shared__ __align__(16) float Bs[4][BWSZ];
  const int wid  = __builtin_amdgcn_readfirstlane((int)(threadIdx.x >> 6));
  const int lane = (int)(threadIdx.x & 63);
  const int ia = lane >> 3;   // 'a' == staging channel
  const int ib = lane & 7;    // 'b' == staging position
  const int wglob = __builtin_amdgcn_readfirstlane((int)blockIdx.x) * 4 + wid;
  const int samp = wglob / G;
  const int g    = wglob - samp * G;
  const int ts = g * CPC;
  const int te = (ts + CPC < NINC) ? (ts + CPC) : NINC;   // exclusive end
  const float* pbase = path + (size_t)samp * (C_ * L_);
  float* as_ = As[wid];
  float* bs  = Bs[wid];

  const int si = ib;
  const float* prow = pbase + ia * L_;
  const int grp = lane & ~7;
  const float* pa = bs + ia * BSTR;
  const float* pb = bs + ib * BSTR;

  // swizzled per-lane A-write pointers (constant for the whole kernel):
  // lane (ia,si) writes step t = h*32 + si*4 + j at swizzled slot
  //   h*32 + si*4 + (j ^ r),  r = (si>>1)&3  (XOR only touches bits[1:0])
  const int rsw = (si >> 1) & 3;
  float* awb = as_ + (ia >> 2) * AHOFF + (ia & 3);
  float* aw0 = awb + (si * 4 + (0 ^ rsw)) * 4;
  float* aw1 = awb + (si * 4 + (1 ^ rsw)) * 4;
  float* aw2 = awb + (si * 4 + (2 ^ rsw)) * 4;
  float* aw3 = awb + (si * 4 + (3 ^ rsw)) * 4;

  f2 S3p[4];
#pragma unroll
  for (int k = 0; k < 4; ++k) S3p[k] = f2{0.f, 0.f};
  float S2 = 0.f, s1a = 0.f;

  const int ntiles = (CPC + TILE - 1) / TILE;   // uniform across grid

  // prologue: prefetch tile 0 + boundary
  float4 r0 = *(const float4*)(prow + ts + si * 4);
  float4 r1 = *(const float4*)(prow + ts + 32 + si * 4);
  float bnd = prow[ts + TILE];

  float4 Ap0, Ap1, Ap2, Ap3, Aq0, Aq1, Aq2, Aq3, Aav, Abv;
  float4 Bp0, Bp1, Bp2, Bp3, Bq0, Bq1, Bq2, Bq3, Bav, Bbv;

  for (int tt = 0; tt < ntiles; ++tt) {
    const int t0 = ts + tt * TILE;
    const int cnt_ = te - t0;
    const int cnt = (cnt_ < TILE) ? cnt_ : TILE;

    // ---- stage tile tt from regs: halved diffs into both LDS layouts ----
    {
      const float4 v0 = r0, v1 = r1;
      const float sA = __shfl(v0.x, lane + 1);
      const float sB = __shfl(v1.x, grp);
      const float sC = __shfl(v1.x, lane + 1);
      const float n0 = (si == 7) ? sB : sA;
      const float n1 = (si == 7) ? bnd : sC;
      float4 d0, d1;
      d0.x = (v0.y - v0.x) * 0.5f;
      d0.y = (v0.z - v0.y) * 0.5f;
      d0.z = (v0.w - v0.z) * 0.5f;
      d0.w = (n0 - v0.w) * 0.5f;
      d1.x = (v1.y - v1.x) * 0.5f;
      d1.y = (v1.z - v1.y) * 0.5f;
      d1.z = (v1.w - v1.z) * 0.5f;
      d1.w = (n1 - v1.w) * 0.5f;
      *(float4*)(bs + ia * BSTR + si * 4) = d0;
      *(float4*)(bs + ia * BSTR + 32 + si * 4) = d1;
      // swizzled transpose writes: d0 at t=si*4+j, d1 at t=32+si*4+j
      aw0[0] = d0.x;
      aw1[0] = d0.y;
      aw2[0] = d0.z;
      aw3[0] = d0.w;
      aw0[128] = d1.x;
      aw1[128] = d1.y;
      aw2[128] = d1.z;
      aw3[128] = d1.w;
    }

    // ---- prefetch tile tt+1 ----
    if (tt + 1 < ntiles) {
      const int t1g = t0 + TILE;
      r0 = *(const float4*)(prow + t1g + si * 4);
      r1 = *(const float4*)(prow + t1g + 32 + si * 4);
      const int bn = t1g + TILE;
      bnd = (bn < L_) ? prow[bn] : 0.f;
    }

    // ---- compute tile tt: 16 4-step blocks, A/B register double-buffer ----
    if (cnt == TILE) {
      LDP(A, 0);
#pragma unroll
      for (int jj = 0; jj < 8; ++jj) {
        LDP(B, jj * 2 + 1);
        CB(A);
        if (jj < 7) { LDP(A, jj * 2 + 2); }
        CB(B);
      }
    } else {
      // tail tile (only the last chunk's last tile, cnt=63): cold path
      for (int blk = 0; blk < 8; ++blk) {
        const int u0 = blk * 8;
        int m = cnt - u0; if (m > 8) m = 8;
        if (m <= 0) break;
        const float4 a0 = *(const float4*)(pa + u0);
        const float4 a1 = *(const float4*)(pa + u0 + 4);
        const float4 b0 = *(const float4*)(pb + u0);
        const float4 b1 = *(const float4*)(pb + u0 + 4);
        const float da[8] = {a0.x, a0.y, a0.z, a0.w, a1.x, a1.y, a1.z, a1.w};
        const float db[8] = {b0.x, b0.y, b0.z, b0.w, b1.x, b1.y, b1.z, b1.w};
#pragma unroll
        for (int u = 0; u < 8; ++u) {
          if (u < m) {
            const int tsw = SW(u0 + u);
            const float4 PLO = *(const float4*)(as_ + tsw * 4);
            const float4 PHI = *(const float4*)(as_ + AHOFF + tsw * 4);
            ST1(da[u], db[u], PLO, PHI);
          }
        }
      }
    }
  }

  float* cs = csig + ((size_t)samp * G + g) * SIGDIM;
  if (ib == 0) cs[ia] = s1a;
  cs[8 + lane] = S2;
  float4 o0, o1;
  o0.x = 2.f * S3p[0].x; o0.y = 2.f * S3p[0].y;
  o0.z = 2.f * S3p[1].x; o0.w = 2.f * S3p[1].y;
  o1.x = 2.f * S3p[2].x; o1.y = 2.f * S3p[2].y;
  o1.z = 2.f * S3p[3].x; o1.w = 2.f * S3p[3].y;
  *(float4*)(cs + 72 + lane * 8)     = o0;
  *(float4*)(cs + 72 + lane * 8 + 4) = o1;
}

__global__ __launch_bounds__(256)
void sig_combine_kernel(const float* __restrict__ csig, float* __restrict__ out, int G) {
  const int wid  = __builtin_amdgcn_readfirstlane((int)(threadIdx.x >> 6));
  const int lane = (int)(threadIdx.x & 63);
  const int ia = lane >> 3, ib = lane & 7;
  const int samp = __builtin_amdgcn_readfirstlane((int)blockIdx.x) * 4 + wid;
  const float* base = csig + (size_t)samp * G * SIGDIM;

  float R1a = base[ia];
  float R2  = base[8 + lane];
  float R3[8];
#pragma unroll
  for (int k = 0; k < 8; ++k) R3[k] = base[72 + lane * 8 + k];

  for (int g = 1; g < G; ++g) {
    const float* T = base + g * SIGDIM;
    float sT1[8];
#pragma unroll
    for (int k = 0; k < 8; ++k) sT1[k] = T[k];
    const float T1a  = T[ia];
    const float T1b  = T[ib];
    const float T2ab = T[8 + lane];
    float T2b[8], T3v[8];
#pragma unroll
    for (int k = 0; k < 8; ++k) T2b[k] = T[8 + ib * 8 + k];
#pragma unroll
    for (int k = 0; k < 8; ++k) T3v[k] = T[72 + lane * 8 + k];
    const float R1o = R1a, R2o = R2;
#pragma unroll
    for (int k = 0; k < 8; ++k)
      R3[k] += T3v[k] + R1o * T2b[k] + R2o * sT1[k];
    R2  += T2ab + R1o * T1b;
    R1a += T1a;
  }

  float* o = out + (size_t)samp * SIGDIM;
  if (ib == 0) o[ia] = R1a;
  o[8 + lane] = R2;
#pragma unroll
  for (int k = 0; k < 8; ++k) o[72 + lane * 8 + k] = R3[k];
}

extern "C" void kernel_launch(void* const* d_in, const int* in_sizes, int n_in,
                              void* d_out, int out_size, void* d_ws, size_t ws_size,
                              hipStream_t stream) {
  (void)in_sizes; (void)n_in; (void)out_size;
  const float* path = (const float*)d_in[0];
  float* out = (float*)d_out;
  float* ws  = (float*)d_ws;

  int G = 16;
  while (G > 1 && (size_t)B_ * G * SIGDIM * sizeof(float) > ws_size) G >>= 1;
  const int CPC = (NINC + G - 1) / G;   // increments per chunk

  sig_chunks_kernel<<<dim3(B_ * G / 4), dim3(256), 0, stream>>>(path, ws, G, CPC);
  sig_combine_kernel<<<dim3(B_ / 4), dim3(256), 0, stream>>>(ws, out, G);
}